// Round 9
// baseline (210.816 us; speedup 1.0000x reference)
//
#include <hip/hip_runtime.h>
#include <cstdint>

// y = clip(round((x @ W^T) * (sx*sw/sy)), -128, 127), M=8192 N=4096 K=4096 int8.
// Pass 1 (pack): int32 -> int8, fragment-major for 128-row panels:
//   [mb (128 rows)][h 0..63 (K/64B)][rf 0..7][lane*16], lane = kl*16+fr ->
//   rows mb*128+rf*16+fr, K-bytes h*64+kl*16..+15 (exact mfma_i32_16x16x64_i8
//   operand order). 512KB per (matrix,mb) panel; 8KB per (mb,h) piece.
// Pass 2 (GEMM): TLP experiment. Rounds 2-8 proved every *schedule* (2-bar,
//   ring-4, 4-phase, 1-bar, private-LDS, LDS-free, 8-phase) lands at 137-140us
//   / MfmaUtil ~43% -- all shared ONE trait: 1 block/CU (correlated waves).
//   Now: 128x128 tile, 256 thr (4 waves, 2x2 of 64x64), LDS 32KB ring-2,
//   __launch_bounds__(256,3) -> 3 INDEPENDENT blocks/CU = 12 waves/CU.
//   When one block stalls at its barrier/vmcnt, the other two feed the
//   matrix pipes. Sync = round-5 minimal proven-correct loop.

#define MDIM 8192
#define NDIM 4096
#define KDIM 4096
#define BM 128
#define BN 128
#define NH 64  // K-chunks of 64 bytes

typedef int v4i __attribute__((ext_vector_type(4)));

#define FENCE() asm volatile("" ::: "memory")
#define BARX()                    \
  do {                            \
    FENCE();                      \
    __builtin_amdgcn_s_barrier(); \
    FENCE();                      \
  } while (0)

__device__ __forceinline__ uint32_t pack4(int a, int b, int c, int d) {
  return (uint32_t)(a & 0xFF) | ((uint32_t)(b & 0xFF) << 8) |
         ((uint32_t)(c & 0xFF) << 16) | ((uint32_t)(d & 0xFF) << 24);
}

// ---------- pack: gather int32 -> fragment-major int8 + scale_y tail ----------
// chunk -> [mb][h][rf][lane]: lane = chunk&63, rf = (chunk>>6)&7,
// h = (chunk>>9)&63, mb = chunk>>15.
__global__ __launch_bounds__(256) void pack_kernel(
    const int* __restrict__ x32, const int* __restrict__ w32,
    const float* __restrict__ sy, uint8_t* __restrict__ x8f,
    uint8_t* __restrict__ w8f, float* __restrict__ tail) {
  const int t = blockIdx.x * 256 + threadIdx.x;
  if (t < NDIM) tail[t] = sy[t];
  const int NXC = (MDIM / 16) * KDIM;  // 2,097,152
  const int NWC = (NDIM / 16) * KDIM;  // 1,048,576
  if (t >= NXC + NWC) return;
  const int* src;
  uint8_t* dst;
  int chunk;
  if (t < NXC) {
    chunk = t;
    src = x32;
    dst = x8f;
  } else {
    chunk = t - NXC;
    src = w32;
    dst = w8f;
  }
  const int lpos = chunk & 63;
  const int rf = (chunk >> 6) & 7;
  const int h = (chunk >> 9) & 63;
  const int mb = chunk >> 15;
  const int kl = lpos >> 4, fr = lpos & 15;
  const int r = mb * 128 + rf * 16 + fr;
  const int k0 = h * 64 + kl * 16;
  const int* s = src + (size_t)r * KDIM + k0;  // 64B-aligned line
  v4i a0 = *(const v4i*)(s + 0);
  v4i a1 = *(const v4i*)(s + 4);
  v4i a2 = *(const v4i*)(s + 8);
  v4i a3 = *(const v4i*)(s + 12);
  v4i o;
  o[0] = (int)pack4(a0[0], a0[1], a0[2], a0[3]);
  o[1] = (int)pack4(a1[0], a1[1], a1[2], a1[3]);
  o[2] = (int)pack4(a2[0], a2[1], a2[2], a2[3]);
  o[3] = (int)pack4(a3[0], a3[1], a3[2], a3[3]);
  *(v4i*)(dst + (size_t)chunk * 16) = o;  // linear, fully coalesced
}

// ---------- main GEMM: 128x128 tile, 4 waves, 3 blocks/CU ----------------------
// LDS ring-2: slot = h&1 -> 16KB: [A 8KB][B 8KB].
__global__ __launch_bounds__(256, 3) void gemm_kernel(
    const uint8_t* __restrict__ A8, const uint8_t* __restrict__ B8,
    const float* __restrict__ sxp, const float* __restrict__ swp,
    const float* __restrict__ syp, float* __restrict__ out) {
  __shared__ __align__(16) uint8_t lds[32768];

  const int tid = threadIdx.x;
  const int lane = tid & 63;
  const int wave = tid >> 6;  // 0..3

  // XCD swizzle: nwg = 2048 (divisible by 8 -> bijective). Each XCD gets a
  // contiguous stripe of 256 wgs = 8 mb-rows x 32 nb (A panels L2-resident).
  const int wg = ((int)blockIdx.x & 7) * 256 + ((int)blockIdx.x >> 3);
  const int mb = wg >> 5;  // 0..63
  const int nb = wg & 31;  // 0..31

  const int wm2 = wave >> 1;  // M-half of block tile
  const int wn2 = wave & 1;   // N-half

  const uint8_t* Abase = A8 + ((size_t)mb << 19);  // 512KB per panel
  const uint8_t* Bbase = B8 + ((size_t)nb << 19);

  const uint32_t tid16 = (uint32_t)tid * 16;
  const uint32_t lane16 = (uint32_t)lane * 16;
  const uint32_t aoff = (uint32_t)(wm2 * 4) << 10;
  const uint32_t boff = 8192u + ((uint32_t)(wn2 * 4) << 10);

  v4i acc[4][4];
#pragma unroll
  for (int i = 0; i < 4; i++)
#pragma unroll
    for (int j = 0; j < 4; j++) acc[i][j] = (v4i){0, 0, 0, 0};

  auto gload = [&](const uint8_t* src, uint32_t ldsoff) {
    __builtin_amdgcn_global_load_lds(
        (const __attribute__((address_space(1))) void*)src,
        (__attribute__((address_space(3))) void*)(lds + ldsoff), 16, 0, 0);
  };
  // stage K-chunk h: A 8KB + B 8KB, 4 loads/thread, linear
  auto stage = [&](int h) {
    const uint32_t lb = (uint32_t)(h & 1) * 16384u;
    const uint8_t* sa = Abase + ((size_t)h << 13) + tid16;
    const uint8_t* sb = Bbase + ((size_t)h << 13) + tid16;
    gload(sa, lb + tid16);
    gload(sa + 4096, lb + 4096u + tid16);
    gload(sb, lb + 8192u + tid16);
    gload(sb + 4096, lb + 12288u + tid16);
  };

  stage(0);

  for (int h = 0; h < NH; ++h) {
    // own loads (issued one full iteration ago) drained, then block-wide sync.
    asm volatile("s_waitcnt vmcnt(0)" ::: "memory");
    BARX();
    // safe: every wave's reads of slot (h+1)&1 (= tile h-1) completed into
    // registers before that wave reached the barrier above.
    if (h + 1 < NH) stage(h + 1);

    const uint8_t* L = lds + (uint32_t)(h & 1) * 16384u;
    v4i af[4], bf[4];
#pragma unroll
    for (int i = 0; i < 4; i++)
      af[i] = *(const v4i*)(L + aoff + (i << 10) + lane16);
#pragma unroll
    for (int j = 0; j < 4; j++)
      bf[j] = *(const v4i*)(L + boff + (j << 10) + lane16);
#pragma unroll
    for (int i = 0; i < 4; i++)
#pragma unroll
      for (int j = 0; j < 4; j++)
        acc[i][j] =
            __builtin_amdgcn_mfma_i32_16x16x64_i8(af[i], bf[j], acc[i][j], 0, 0, 0);
  }

  // epilogue: requantize, round-half-even, clip, store float
  const float s = sxp[0] * swp[0];
  const int kl = lane >> 4;
  const int fr = lane & 15;
  const int wrow = mb * 128 + wm2 * 64;
  const int wcol = nb * 128 + wn2 * 64;
#pragma unroll
  for (int j = 0; j < 4; j++) {
    const int col = wcol + j * 16 + fr;
    const float rs = s / syp[col];
#pragma unroll
    for (int i = 0; i < 4; i++) {
      const int row0 = wrow + i * 16 + kl * 4;
#pragma unroll
      for (int r = 0; r < 4; r++) {
        float v = rintf((float)acc[i][j][r] * rs);
        v = fminf(127.f, fmaxf(-128.f, v));
        out[(size_t)(row0 + r) * NDIM + col] = v;
      }
    }
  }
}

extern "C" void kernel_launch(void* const* d_in, const int* in_sizes, int n_in,
                              void* d_out, int out_size, void* d_ws, size_t ws_size,
                              hipStream_t stream) {
  const int* x32 = (const int*)d_in[0];
  const int* w32 = (const int*)d_in[1];
  const float* sx = (const float*)d_in[2];
  const float* sw = (const float*)d_in[3];
  const float* sy = (const float*)d_in[4];
  float* out = (float*)d_out;
  float* tail = out + (size_t)MDIM * NDIM;

  uint8_t* x8f = (uint8_t*)d_ws;
  uint8_t* w8f = x8f + (size_t)MDIM * KDIM;

  const int total = (MDIM / 16) * KDIM + (NDIM / 16) * KDIM;  // 3,145,728
  pack_kernel<<<total / 256, 256, 0, stream>>>(x32, w32, sy, x8f, w8f, tail);

  const int nblocks = (MDIM / BM) * (NDIM / BN);  // 2048
  gemm_kernel<<<nblocks, 256, 0, stream>>>(x8f, w8f, sx, sw, sy, out);
}

// Round 10
// 184.228 us; speedup vs baseline: 1.1443x; 1.1443x over previous
//
#include <hip/hip_runtime.h>
#include <cstdint>

// y = clip(round((x @ W^T) * (sx*sw/sy)), -128, 127), M=8192 N=4096 K=4096 int8.
// Pass 1 (pack): int32 -> int8, fragment-major (rounds 6/7 layout, verified):
//   [mb (256 rows)][h 0..63 (K/64B)][rf 0..15][lane*16], lane = kl*16+fr ->
//   rows mb*256+rf*16+fr, K-bytes h*64+kl*16..+15 (exact mfma_i32_16x16x64_i8
//   operand order; conflict-free ds_read_b128 at region + lane*16).
// Pass 2 (GEMM): the round-3..8 serial-sum (LDS phase alternates with MFMA
//   phase, 5138 cyc/tile) is a PER-WAVE DEPENDENCE problem: read(t)->MFMA(t).
//   Fix = register fragment double-buffer: MFMA(F0 of subtile t) runs while
//   ds_reads fill F1 with subtile t+1 (independent regs) -> LDS port drains
//   under the MFMA cluster within each wave. LDS still stages tiles (keeps
//   L2 feed at 25 B/cyc vs round 7's 49 > 56 ceiling).
//   256x256 tile, 8 waves (2Mx4N, 128x64, acc 8x4), BK=64B, LDS ring-2 32KB
//   (64KB total), counted vmcnt(4) (never 0 mid-loop), lgkm0-before-BAR
//   protects ring overwrite, wait-then-barrier for DMA visibility.

#define MDIM 8192
#define NDIM 4096
#define KDIM 4096
#define BM 256
#define BN 256
#define NH 64  // K-subtiles of 64 bytes

typedef int v4i __attribute__((ext_vector_type(4)));

#define FENCE() asm volatile("" ::: "memory")
#define BARX()                    \
  do {                            \
    FENCE();                      \
    __builtin_amdgcn_s_barrier(); \
    FENCE();                      \
  } while (0)
#define LGKM0() asm volatile("s_waitcnt lgkmcnt(0)" ::: "memory")
#define VMCNT4() asm volatile("s_waitcnt vmcnt(4)" ::: "memory")
#define VMCNT0() asm volatile("s_waitcnt vmcnt(0)" ::: "memory")

__device__ __forceinline__ uint32_t pack4(int a, int b, int c, int d) {
  return (uint32_t)(a & 0xFF) | ((uint32_t)(b & 0xFF) << 8) |
         ((uint32_t)(c & 0xFF) << 16) | ((uint32_t)(d & 0xFF) << 24);
}

// ---------- pack: gather int32 -> fragment-major int8 + scale_y tail ----------
__global__ __launch_bounds__(256) void pack_kernel(
    const int* __restrict__ x32, const int* __restrict__ w32,
    const float* __restrict__ sy, uint8_t* __restrict__ x8f,
    uint8_t* __restrict__ w8f, float* __restrict__ tail) {
  const int t = blockIdx.x * 256 + threadIdx.x;
  if (t < NDIM) tail[t] = sy[t];
  const int NXC = (MDIM / 16) * KDIM;  // 2,097,152
  const int NWC = (NDIM / 16) * KDIM;  // 1,048,576
  if (t >= NXC + NWC) return;
  const int* src;
  uint8_t* dst;
  int chunk;
  if (t < NXC) {
    chunk = t;
    src = x32;
    dst = x8f;
  } else {
    chunk = t - NXC;
    src = w32;
    dst = w8f;
  }
  const int lpos = chunk & 63;       // lane
  const int rf = (chunk >> 6) & 15;  // 16-row fragment
  const int h = (chunk >> 10) & 63;  // K-subtile (64 bytes)
  const int mb = chunk >> 16;        // 256-row block
  const int kl = lpos >> 4, fr = lpos & 15;
  const int r = mb * 256 + rf * 16 + fr;
  const int k0 = h * 64 + kl * 16;
  const int* s = src + (size_t)r * KDIM + k0;  // 64B-aligned line
  v4i a0 = *(const v4i*)(s + 0);
  v4i a1 = *(const v4i*)(s + 4);
  v4i a2 = *(const v4i*)(s + 8);
  v4i a3 = *(const v4i*)(s + 12);
  v4i o;
  o[0] = (int)pack4(a0[0], a0[1], a0[2], a0[3]);
  o[1] = (int)pack4(a1[0], a1[1], a1[2], a1[3]);
  o[2] = (int)pack4(a2[0], a2[1], a2[2], a2[3]);
  o[3] = (int)pack4(a3[0], a3[1], a3[2], a3[3]);
  *(v4i*)(dst + (size_t)chunk * 16) = o;  // linear, fully coalesced
}

// ---------- main GEMM: register-frag double-buffer over LDS ring-2 -------------
// 512 threads = 8 waves (2M x 4N), per-wave output 128x64, acc 8x4 frags.
// LDS: 2 slots x 32KB (slot = h&1): [A 16KB][B 16KB].
__global__ __launch_bounds__(512, 2) void gemm_kernel(
    const uint8_t* __restrict__ A8, const uint8_t* __restrict__ B8,
    const float* __restrict__ sxp, const float* __restrict__ swp,
    const float* __restrict__ syp, float* __restrict__ out) {
  __shared__ __align__(16) uint8_t lds[65536];

  const int tid = threadIdx.x;
  const int lane = tid & 63;
  const int wave = tid >> 6;

  // XCD-aware swizzle: nwg = 512 (divisible by 8 -> bijective)
  const int wg = ((int)blockIdx.x % 8) * 64 + (int)blockIdx.x / 8;
  const int mb = wg >> 4;  // 0..31
  const int nb = wg & 15;  // 0..15

  const int wm2 = wave >> 2;  // 0..1
  const int wn4 = wave & 3;   // 0..3

  const uint8_t* Abase = A8 + ((size_t)mb << 20);
  const uint8_t* Bbase = B8 + ((size_t)nb << 20);

  const uint32_t tid16 = (uint32_t)tid * 16;
  const uint32_t lane16 = (uint32_t)lane * 16;
  const uint32_t aoff = ((uint32_t)(wm2 * 8) << 10) + lane16;
  const uint32_t boff = 16384u + ((uint32_t)(wn4 * 4) << 10) + lane16;

  v4i acc[8][4];
#pragma unroll
  for (int i = 0; i < 8; i++)
#pragma unroll
    for (int j = 0; j < 4; j++) acc[i][j] = (v4i){0, 0, 0, 0};

  auto gload = [&](const uint8_t* src, uint32_t ldsoff) {
    __builtin_amdgcn_global_load_lds(
        (const __attribute__((address_space(1))) void*)src,
        (__attribute__((address_space(3))) void*)(lds + ldsoff), 16, 0, 0);
  };
  // stage subtile h (A 16KB + B 16KB), 4 loads/thread, all linear
  auto stage = [&](int h) {
    const uint32_t lb = (uint32_t)(h & 1) * 32768u;
    const uint8_t* sa = Abase + ((size_t)h << 14) + tid16;
    const uint8_t* sb = Bbase + ((size_t)h << 14) + tid16;
    gload(sa, lb + tid16);
    gload(sa + 8192, lb + 8192u + tid16);
    gload(sb, lb + 16384u + tid16);
    gload(sb + 8192, lb + 24576u + tid16);
  };

  v4i af0[8], bf0[4], af1[8], bf1[4];

#define READ_FRAGS(AF, BF, SB)                                   \
  do {                                                           \
    _Pragma("unroll") for (int i = 0; i < 8; i++) AF[i] =        \
        *(const v4i*)(lds + (SB) + aoff + (i << 10));            \
    _Pragma("unroll") for (int j = 0; j < 4; j++) BF[j] =        \
        *(const v4i*)(lds + (SB) + boff + (j << 10));            \
  } while (0)

#define MFMA32(AF, BF)                                                        \
  do {                                                                        \
    _Pragma("unroll") for (int i = 0; i < 8; i++) _Pragma(                    \
        "unroll") for (int j = 0; j < 4; j++) acc[i][j] =                     \
        __builtin_amdgcn_mfma_i32_16x16x64_i8(AF[i], BF[j], acc[i][j], 0, 0, \
                                              0);                             \
  } while (0)

  // prologue: subtiles 0,1 staged; frags(0) -> F0
  stage(0);
  stage(1);
  VMCNT4();  // DMA(0) landed (own); BAR makes it CU-visible
  BARX();
  READ_FRAGS(af0, bf0, 0u);

  // steady state: 31 iterations, each processes subtiles h (F0) and h+1 (F1)
  for (int h = 0; h < 62; h += 2) {
    LGKM0();  // own frags(h) reads complete
    BARX();   // all waves done reading slot0 -> safe to overwrite
    stage(h + 2);
    VMCNT4();  // DMA(h+1) landed (own)
    BARX();    // CU-visible
    READ_FRAGS(af1, bf1, 32768u);  // frags(h+1); independent of MFMA below
    MFMA32(af0, bf0);              // compute subtile h under the reads

    LGKM0();  // own frags(h+1) reads complete
    BARX();   // all waves done reading slot1
    stage(h + 3);
    VMCNT4();  // DMA(h+2) landed
    BARX();
    READ_FRAGS(af0, bf0, 0u);  // frags(h+2)
    MFMA32(af1, bf1);          // compute subtile h+1 under the reads
  }

  // tail: h = 62 (F0 = frags(62)); DMA(63) still in flight (4 outstanding)
  LGKM0();
  BARX();
  VMCNT0();  // DMA(63) landed
  BARX();
  READ_FRAGS(af1, bf1, 32768u);  // frags(63)
  MFMA32(af0, bf0);              // subtile 62
  MFMA32(af1, bf1);              // subtile 63 (compiler inserts lgkm wait)

  // epilogue: requantize, round-half-even, clip, store float
  const float s = sxp[0] * swp[0];
  const int kl = lane >> 4;
  const int fr = lane & 15;
  const int wrow = mb * 256 + wm2 * 128;
  const int wcol = nb * 256 + wn4 * 64;
#pragma unroll
  for (int j = 0; j < 4; j++) {
    const int col = wcol + j * 16 + fr;
    const float rs = s / syp[col];
#pragma unroll
    for (int i = 0; i < 8; i++) {
      const int row0 = wrow + i * 16 + kl * 4;
#pragma unroll
      for (int r = 0; r < 4; r++) {
        float v = rintf((float)acc[i][j][r] * rs);
        v = fminf(127.f, fmaxf(-128.f, v));
        out[(size_t)(row0 + r) * NDIM + col] = v;
      }
    }
  }
}

extern "C" void kernel_launch(void* const* d_in, const int* in_sizes, int n_in,
                              void* d_out, int out_size, void* d_ws, size_t ws_size,
                              hipStream_t stream) {
  const int* x32 = (const int*)d_in[0];
  const int* w32 = (const int*)d_in[1];
  const float* sx = (const float*)d_in[2];
  const float* sw = (const float*)d_in[3];
  const float* sy = (const float*)d_in[4];
  float* out = (float*)d_out;
  float* tail = out + (size_t)MDIM * NDIM;

  uint8_t* x8f = (uint8_t*)d_ws;
  uint8_t* w8f = x8f + (size_t)MDIM * KDIM;

  const int total = (MDIM / 16) * KDIM + (NDIM / 16) * KDIM;  // 3,145,728
  pack_kernel<<<total / 256, 256, 0, stream>>>(x32, w32, sy, x8f, w8f, tail);

  const int nblocks = (MDIM / BM) * (NDIM / BN);  // 512
  gemm_kernel<<<nblocks, 512, 0, stream>>>(x8f, w8f, sx, sw, sy, out);
}